// Round 1
// baseline (201.492 us; speedup 1.0000x reference)
//
#include <hip/hip_runtime.h>

#define BATCH   1048576
#define IN_DIM  64
#define OUT_DIM 16

// ---------------------------------------------------------------------------
// Kernel 1: G = (A A^T)^-1  (16x16), C = G*A (16x64), written to workspace.
// Single block, 256 threads. Gauss-Jordan with partial pivoting in LDS.
// ---------------------------------------------------------------------------
__global__ __launch_bounds__(256) void precompute_kernel(
    const float* __restrict__ A, float* __restrict__ GC)
{
    __shared__ float sA[16][64];
    __shared__ float M[16][32];   // [S | I]
    __shared__ float fac[16];
    __shared__ int piv;

    const int tid = threadIdx.x;

    for (int i = tid; i < 1024; i += 256) sA[i >> 6][i & 63] = A[i];
    __syncthreads();

    // S = A A^T, augmented with identity
    {
        const int i = tid >> 4, j = tid & 15;
        float s = 0.f;
        #pragma unroll
        for (int k = 0; k < 64; ++k) s = fmaf(sA[i][k], sA[j][k], s);
        M[i][j] = s;
        M[i][16 + j] = (i == j) ? 1.f : 0.f;
    }
    __syncthreads();

    for (int p = 0; p < 16; ++p) {
        if (tid == 0) {
            int best = p;
            float bv = fabsf(M[p][p]);
            for (int r = p + 1; r < 16; ++r) {
                float v = fabsf(M[r][p]);
                if (v > bv) { bv = v; best = r; }
            }
            piv = best;
        }
        __syncthreads();
        if (tid < 32) {
            const int pr = piv;
            if (pr != p) { float t = M[p][tid]; M[p][tid] = M[pr][tid]; M[pr][tid] = t; }
        }
        __syncthreads();
        const float pv = M[p][p];      // every thread snapshots pivot value
        __syncthreads();               // all reads done before row-p write
        if (tid < 32) M[p][tid] *= (1.0f / pv);
        __syncthreads();
        if (tid < 16) fac[tid] = M[tid][p];   // column-p snapshot per row
        __syncthreads();
        for (int e = tid; e < 512; e += 256) {
            const int r = e >> 5, c = e & 31;
            if (r != p) M[r][c] = fmaf(-fac[r], M[p][c], M[r][c]);
        }
        __syncthreads();
    }

    // G  -> GC[0:256)
    {
        const int i = tid >> 4, j = tid & 15;
        GC[tid] = M[i][16 + j];
    }
    // C = G*A -> GC[256:1280)
    for (int e = tid; e < 1024; e += 256) {
        const int i = e >> 6, k = e & 63;
        float s = 0.f;
        #pragma unroll
        for (int j = 0; j < 16; ++j) s = fmaf(M[i][16 + j], sA[j][k], s);
        GC[256 + e] = s;
    }
}

// ---------------------------------------------------------------------------
// Kernel 2: per-row  x = y - A^T * ( C*y - G*b ).
// One thread per row; float4 global access; matrices broadcast from LDS.
// ---------------------------------------------------------------------------
__global__ __launch_bounds__(256) void apply_kernel(
    const float* __restrict__ y, const float* __restrict__ b,
    const float* __restrict__ A, const float* __restrict__ GC,
    float* __restrict__ out)
{
    __shared__ float sC[16][64];   // C = G*A
    __shared__ float sG[16][16];   // G
    __shared__ float sAT[64][16];  // A^T

    const int tid = threadIdx.x;
    for (int i = tid; i < 1024; i += 256) {
        const int r = i >> 6, c = i & 63;
        const float a = A[i];
        sC[r][c] = GC[256 + i];
        sAT[c][r] = a;
    }
    sG[tid >> 4][tid & 15] = GC[tid];
    __syncthreads();

    const size_t row = (size_t)blockIdx.x * 256 + tid;
    const float4* y4 = reinterpret_cast<const float4*>(y) + row * 16;
    const float4* b4 = reinterpret_cast<const float4*>(b) + row * 4;

    float yr[64];
    #pragma unroll
    for (int q = 0; q < 16; ++q) {
        const float4 v = y4[q];
        yr[4*q+0] = v.x; yr[4*q+1] = v.y; yr[4*q+2] = v.z; yr[4*q+3] = v.w;
    }
    float br[16];
    #pragma unroll
    for (int q = 0; q < 4; ++q) {
        const float4 v = b4[q];
        br[4*q+0] = v.x; br[4*q+1] = v.y; br[4*q+2] = v.z; br[4*q+3] = v.w;
    }

    // mu = C*y - G*b
    float mu[16];
    #pragma unroll
    for (int j = 0; j < 16; ++j) {
        float acc = 0.f;
        #pragma unroll
        for (int k = 0; k < 64; ++k) acc = fmaf(sC[j][k], yr[k], acc);
        #pragma unroll
        for (int i = 0; i < 16; ++i) acc = fmaf(-sG[j][i], br[i], acc);
        mu[j] = acc;
    }

    // x = y - A^T * mu
    #pragma unroll
    for (int k = 0; k < 64; ++k) {
        float acc = yr[k];
        #pragma unroll
        for (int j = 0; j < 16; ++j) acc = fmaf(-sAT[k][j], mu[j], acc);
        yr[k] = acc;
    }

    float4* o4 = reinterpret_cast<float4*>(out) + row * 16;
    #pragma unroll
    for (int q = 0; q < 16; ++q) {
        o4[q] = make_float4(yr[4*q+0], yr[4*q+1], yr[4*q+2], yr[4*q+3]);
    }
}

// ---------------------------------------------------------------------------
extern "C" void kernel_launch(void* const* d_in, const int* in_sizes, int n_in,
                              void* d_out, int out_size, void* d_ws, size_t ws_size,
                              hipStream_t stream) {
    const float* y = (const float*)d_in[0];   // (1048576, 64)
    const float* A = (const float*)d_in[1];   // (16, 64)
    const float* b = (const float*)d_in[2];   // (1048576, 16)
    float* out = (float*)d_out;               // (1048576, 64)
    float* GC  = (float*)d_ws;                // 1280 floats: G(256) + C(1024)

    precompute_kernel<<<1, 256, 0, stream>>>(A, GC);
    apply_kernel<<<BATCH / 256, 256, 0, stream>>>(y, b, A, GC, out);
}